// Round 4
// baseline (45.665 us; speedup 1.0000x reference)
//
#include <hip/hip_runtime.h>

typedef int int4v __attribute__((ext_vector_type(4)));

// Problem constants
#define IN_C    64
#define OUT_C   128
#define NPIX    200704      // 64*56*56
#define KTOT    576         // 3*3*64
#define N_W     73728       // 128*3*3*64
#define N_OUT   25690112    // NPIX * OUT_C

// Halo tiling: 2 images x 8x8 output pixels per block, 2 x 10x10 halo in LDS.
#define PIXB    80          // bytes per halo pixel slot (64 data + 16 pad)
// halo LDS = 200 * 80 = 16000 B

// ---------------------------------------------------------------------------
// Pack weights into fragment order for mfma_i32_16x16x64_i8:
//   dest byte t = ((kt*8 + nt)*64 + lane)*16 + byte
//   holds W[k][n] with k = kt*64 + (lane>>4)*16 + byte, n = nt*16 + (lane&15)
// Source OHWI flat index = n*576 + k  (since k = (kh*3+kw)*64+ic).
// Used as the A operand (M=channels); lane&15 = channel-in-chunk.
__global__ __launch_bounds__(256) void pack_w_kernel(const int* __restrict__ wgt,
                                                     char* __restrict__ w8) {
    int t = blockIdx.x * 256 + threadIdx.x;   // t < N_W == 73728 exactly
    int byte = t & 15;
    int lane = (t >> 4) & 63;
    int ntk  = t >> 10;
    int nt   = ntk & 7;
    int kt   = ntk >> 3;                      // kt < 9
    int k = kt * 64 + ((lane >> 4) << 4) + byte;
    int n = nt * 16 + (lane & 15);
    w8[t] = (char)wgt[n * KTOT + k];
}

// ---------------------------------------------------------------------------
// Halo-tile MFMA conv. Block = 2 images x (8x8 pixels) x 128 channels, 4 waves.
// MFMA operands SWAPPED vs naive: A = weights (M=16 channels), B = x pixels
// (N=16 pixels) -> D row = channel, col = pixel -> dwordx4 epilogue stores.
__global__ __launch_bounds__(256, 4) void conv_halo2_kernel(const int* __restrict__ x32,
                                                            const char* __restrict__ w8,
                                                            const int* __restrict__ bias,
                                                            int* __restrict__ out) {
    __shared__ char hx[200 * PIXB];

    const int tid  = threadIdx.x;
    const int lane = tid & 63;
    const int wv   = tid >> 6;
    const int l15  = lane & 15;
    const int l4   = lane >> 4;

    // block -> (image pair, th, tw); 7x7 tiles per image
    const int bid  = blockIdx.x;
    const int pair = bid / 49;
    const int rr   = bid - pair * 49;
    const int th   = rr / 7;
    const int tw   = rr - th * 7;
    const int n0   = pair * 2;
    const int h0   = th * 8 - 1;              // halo origin (may be -1)
    const int w0   = tw * 8 - 1;

    // ---- Stage halo: 2 x 100 px x 4 quarters = 800 units; unit = 16B int8.
    for (int u = tid; u < 800; u += 256) {
        int pix = u >> 2;                 // 0..199
        int q   = u & 3;
        int im  = pix >= 100;
        int lp  = pix - im * 100;
        int hr  = lp / 10;
        int hc  = lp - hr * 10;
        int gh  = h0 + hr;
        int gw  = w0 + hc;
        int4v pk = {0, 0, 0, 0};
        if ((unsigned)gh < 56u && (unsigned)gw < 56u) {
            const int4v* src = (const int4v*)x32
                             + ((((n0 + im) * 56 + gh) * 56 + gw) << 4) + (q << 2);
            int4v a0 = src[0], a1 = src[1], a2 = src[2], a3 = src[3];
            pk.x = (a0.x & 0xff) | ((a0.y & 0xff) << 8) | ((a0.z & 0xff) << 16) | (a0.w << 24);
            pk.y = (a1.x & 0xff) | ((a1.y & 0xff) << 8) | ((a1.z & 0xff) << 16) | (a1.w << 24);
            pk.z = (a2.x & 0xff) | ((a2.y & 0xff) << 8) | ((a2.z & 0xff) << 16) | (a2.w << 24);
            pk.w = (a3.x & 0xff) | ((a3.y & 0xff) << 8) | ((a3.z & 0xff) << 16) | (a3.w << 24);
        }
        *(int4v*)(hx + pix * PIXB + (q << 4)) = pk;
    }
    __syncthreads();

    // ---- Per-lane LDS base: pixel-in-16-chunk = l15 -> (pr,pc); l4 = k quarter.
    const char* aptr = hx + ((l15 >> 3) * 10 + (l15 & 7)) * PIXB + (l4 << 4);

    int4v acc[8][2];
#pragma unroll
    for (int mt = 0; mt < 8; ++mt) {
        acc[mt][0] = (int4v){0, 0, 0, 0};
        acc[mt][1] = (int4v){0, 0, 0, 0};
    }

    // Weight fragment stream: kt stride 8192B, ntl stride 1024B, 1-deep prefetch.
    const char* wp = w8 + (((wv * 2) * 64 + lane) << 4);
    int4v bc0 = *(const int4v*)(wp);
    int4v bc1 = *(const int4v*)(wp + 1024);
    int toff = 0;
#pragma unroll 1
    for (int kt = 0; kt < 9; ++kt) {
        wp += 8192;
        int4v bn0 = bc0, bn1 = bc1;
        if (kt < 8) {
            bn0 = *(const int4v*)(wp);
            bn1 = *(const int4v*)(wp + 1024);
        }
#pragma unroll
        for (int mt = 0; mt < 8; ++mt) {
            int4v a = *(const int4v*)(aptr + toff + (mt & 3) * 1600 + (mt >> 2) * 8000);
            // swapped operands: weights = A (channels), x = B (pixels)
            acc[mt][0] = __builtin_amdgcn_mfma_i32_16x16x64_i8(bc0, a, acc[mt][0], 0, 0, 0);
            acc[mt][1] = __builtin_amdgcn_mfma_i32_16x16x64_i8(bc1, a, acc[mt][1], 0, 0, 0);
        }
        bc0 = bn0;
        bc1 = bn1;
        toff += 80;                       // next kw
        if ((kt == 2) | (kt == 5)) toff += 560;  // next kh row (800 total)
    }

    // ---- Epilogue: D row = 4*l4+r = channel offset, col = l15 = pixel.
    // Lane holds 4 consecutive channels -> int4v stores.
    const int chb = wv * 32 + (l4 << 2);
    int4v bv0 = *(const int4v*)(bias + chb);
    int4v bv1 = *(const int4v*)(bias + chb + 16);
    int* ob0 = out + (((n0 * 56 + th * 8) * 56 + tw * 8) << 7);
    int* ob1 = ob0 + (3136 << 7);         // next image
    const int pc = l15 & 7;
#pragma unroll
    for (int mt = 0; mt < 8; ++mt) {
        int pr = ((mt & 3) << 1) + (l15 >> 3);
        int* ob = ((mt < 4) ? ob0 : ob1) + ((pr * 56 + pc) << 7) + chb;
        *(int4v*)(ob)      = acc[mt][0] + bv0;
        *(int4v*)(ob + 16) = acc[mt][1] + bv1;
    }
}

// ---------------------------------------------------------------------------
// Fallback (only if workspace is too small): direct conv, 1 thread/output.
__global__ __launch_bounds__(256) void conv_naive_kernel(const int* __restrict__ x,
                                                         const int* __restrict__ wgt,
                                                         const int* __restrict__ bias,
                                                         int* __restrict__ out) {
    int idx = blockIdx.x * 256 + threadIdx.x;
    if (idx >= N_OUT) return;
    int ch  = idx & 127;
    int pix = idx >> 7;
    int n  = pix / 3136;
    int r2 = pix - n * 3136;
    int h  = r2 / 56;
    int w  = r2 - h * 56;
    int acc = bias[ch];
    for (int kh = 0; kh < 3; ++kh) {
        int hxr = h + kh - 1;
        if ((unsigned)hxr >= 56u) continue;
        for (int kw = 0; kw < 3; ++kw) {
            int wx = w + kw - 1;
            if ((unsigned)wx >= 56u) continue;
            const int* xp = x + ((n * 56 + hxr) * 56 + wx) * 64;
            const int* wp = wgt + ch * KTOT + (kh * 3 + kw) * 64;
            for (int ic = 0; ic < 64; ++ic) acc += xp[ic] * wp[ic];
        }
    }
    out[idx] = acc;
}

// ---------------------------------------------------------------------------
extern "C" void kernel_launch(void* const* d_in, const int* in_sizes, int n_in,
                              void* d_out, int out_size, void* d_ws, size_t ws_size,
                              hipStream_t stream) {
    const int* x    = (const int*)d_in[0];
    const int* wgt  = (const int*)d_in[1];
    const int* bias = (const int*)d_in[2];
    int* out = (int*)d_out;

    if (ws_size >= (size_t)N_W) {
        char* w8 = (char*)d_ws;              // N_W bytes, fragment order
        pack_w_kernel<<<N_W / 256, 256, 0, stream>>>(wgt, w8);
        conv_halo2_kernel<<<32 * 49, 256, 0, stream>>>(x, w8, bias, out);
    } else {
        conv_naive_kernel<<<(N_OUT + 255) / 256, 256, 0, stream>>>(x, wgt, bias, out);
    }
}

// Round 5
// 41.637 us; speedup vs baseline: 1.0968x; 1.0968x over previous
//
#include <hip/hip_runtime.h>

typedef int int4v __attribute__((ext_vector_type(4)));

// Problem constants
#define IN_C    64
#define OUT_C   128
#define NPIX    200704      // 64*56*56
#define KTOT    576         // 3*3*64
#define N_W     73728       // 128*3*3*64
#define N_OUT   25690112    // NPIX * OUT_C

// Halo tiling: 8x8 output pixels per block, 10x10 halo in LDS.
#define PIXB    80          // bytes per halo pixel slot (64 data + 16 pad)
// halo LDS = 100 * 80 = 8000 B

// ---------------------------------------------------------------------------
// Pack weights into fragment order for mfma_i32_16x16x64_i8 (vectorized:
// one thread produces 4 dest bytes = 1 dword, reads 4 consecutive-k int32).
//   dest byte t = ((kt*8 + nt)*64 + lane)*16 + byte
//   holds W[k][n] with k = kt*64 + (lane>>4)*16 + byte, n = nt*16 + (lane&15)
// Source OHWI flat index = n*576 + k.
__global__ __launch_bounds__(256) void pack_w_kernel(const int* __restrict__ wgt,
                                                     unsigned int* __restrict__ w8) {
    int t = blockIdx.x * 256 + threadIdx.x;   // t < 18432 exactly
    int d = t << 2;
    int byte = d & 15;                        // 0,4,8,12
    int lane = (d >> 4) & 63;
    int ntk  = d >> 10;
    int nt   = ntk & 7;
    int kt   = ntk >> 3;                      // kt < 9
    int k = kt * 64 + ((lane >> 4) << 4) + byte;   // multiple of 4
    int n = nt * 16 + (lane & 15);
    int4v v = *(const int4v*)(wgt + n * KTOT + k);
    w8[t] = (v.x & 0xff) | ((v.y & 0xff) << 8) | ((v.z & 0xff) << 16)
          | ((unsigned int)v.w << 24);
}

// ---------------------------------------------------------------------------
// Halo-tile MFMA conv. Block = 8x8 pixels x 128 channels, 4 waves.
// Operands swapped: A = weights (M=channels), B = x pixels (N=pixels)
// -> D row = channel, col = pixel -> each lane holds 4 consecutive channels
// -> dwordx4 epilogue stores + vectorized bias.
__global__ __launch_bounds__(256, 4) void conv_halo_kernel(const int* __restrict__ x32,
                                                           const char* __restrict__ w8,
                                                           const int* __restrict__ bias,
                                                           int* __restrict__ out) {
    __shared__ char hx[100 * PIXB];

    const int tid  = threadIdx.x;
    const int lane = tid & 63;
    const int wv   = tid >> 6;
    const int l15  = lane & 15;
    const int l4   = lane >> 4;

    // XCD-chunked bijective swizzle: grid 3136 = 8 XCDs x 392.
    // 392 = 8 whole images per XCD -> neighbor tiles share halo in same L2.
    const int bid = blockIdx.x;
    const int nb  = (bid & 7) * 392 + (bid >> 3);

    const int n   = nb / 49;
    const int rr  = nb - n * 49;
    const int th  = rr / 7;
    const int tw  = rr - th * 7;
    const int h0  = th * 8 - 1;               // halo origin (may be -1)
    const int w0  = tw * 8 - 1;

    // ---- Stage halo: 100 px * 4 quarters = 400 units; unit = 16B int8 out.
    for (int u = tid; u < 400; u += 256) {
        int pix = u >> 2;
        int q   = u & 3;
        int hr  = pix / 10;
        int hc  = pix - hr * 10;
        int gh  = h0 + hr;
        int gw  = w0 + hc;
        int4v pk = {0, 0, 0, 0};
        if ((unsigned)gh < 56u && (unsigned)gw < 56u) {
            const int4v* src = (const int4v*)x32 + (((n * 56 + gh) * 56 + gw) << 4) + (q << 2);
            int4v a0 = src[0], a1 = src[1], a2 = src[2], a3 = src[3];
            pk.x = (a0.x & 0xff) | ((a0.y & 0xff) << 8) | ((a0.z & 0xff) << 16) | (a0.w << 24);
            pk.y = (a1.x & 0xff) | ((a1.y & 0xff) << 8) | ((a1.z & 0xff) << 16) | (a1.w << 24);
            pk.z = (a2.x & 0xff) | ((a2.y & 0xff) << 8) | ((a2.z & 0xff) << 16) | (a2.w << 24);
            pk.w = (a3.x & 0xff) | ((a3.y & 0xff) << 8) | ((a3.z & 0xff) << 16) | (a3.w << 24);
        }
        *(int4v*)(hx + pix * PIXB + (q << 4)) = pk;
    }
    __syncthreads();

    // ---- Per-lane LDS base: pixel-in-chunk = l15 -> (pr,pc); l4 = k quarter.
    const char* aptr = hx + ((l15 >> 3) * 10 + (l15 & 7)) * PIXB + (l4 << 4);

    int4v acc[4][2];
#pragma unroll
    for (int mt = 0; mt < 4; ++mt) {
        acc[mt][0] = (int4v){0, 0, 0, 0};
        acc[mt][1] = (int4v){0, 0, 0, 0};
    }

    // Weight fragment stream: kt stride 8192B, ntl stride 1024B, 1-deep
    // unconditional prefetch (workspace has an 8KB scratch tail).
    const char* wp = w8 + (((wv * 2) * 64 + lane) << 4);
    int4v bc0 = *(const int4v*)(wp);
    int4v bc1 = *(const int4v*)(wp + 1024);
    int toff = 0;
#pragma unroll 1
    for (int kt = 0; kt < 9; ++kt) {
        wp += 8192;
        int4v bn0 = *(const int4v*)(wp);          // kt=8 load is dead scratch
        int4v bn1 = *(const int4v*)(wp + 1024);
#pragma unroll
        for (int mt = 0; mt < 4; ++mt) {
            int4v a = *(const int4v*)(aptr + toff + mt * 1600);
            // swapped: weights = A (channels), x = B (pixels)
            acc[mt][0] = __builtin_amdgcn_mfma_i32_16x16x64_i8(bc0, a, acc[mt][0], 0, 0, 0);
            acc[mt][1] = __builtin_amdgcn_mfma_i32_16x16x64_i8(bc1, a, acc[mt][1], 0, 0, 0);
        }
        bc0 = bn0;
        bc1 = bn1;
        toff += 80;                       // next kw
        if ((kt == 2) | (kt == 5)) toff += 560;  // next kh row (800 total)
    }

    // ---- Epilogue: D row = 4*l4+r = channel-in-16, col = l15 = pixel-in-16.
    const int chb = wv * 32 + (l4 << 2);
    int4v bv0 = *(const int4v*)(bias + chb);
    int4v bv1 = *(const int4v*)(bias + chb + 16);
    int* ob = out + (((n * 56 + th * 8) * 56 + tw * 8) << 7);
    const int pc = l15 & 7;
    const int prl = l15 >> 3;
#pragma unroll
    for (int mt = 0; mt < 4; ++mt) {
        int pr = (mt << 1) + prl;
        int* o = ob + ((pr * 56 + pc) << 7) + chb;
        *(int4v*)(o)      = acc[mt][0] + bv0;
        *(int4v*)(o + 16) = acc[mt][1] + bv1;
    }
}

// ---------------------------------------------------------------------------
// Fallback (only if workspace is too small): direct conv, 1 thread/output.
__global__ __launch_bounds__(256) void conv_naive_kernel(const int* __restrict__ x,
                                                         const int* __restrict__ wgt,
                                                         const int* __restrict__ bias,
                                                         int* __restrict__ out) {
    int idx = blockIdx.x * 256 + threadIdx.x;
    if (idx >= N_OUT) return;
    int ch  = idx & 127;
    int pix = idx >> 7;
    int n  = pix / 3136;
    int r2 = pix - n * 3136;
    int h  = r2 / 56;
    int w  = r2 - h * 56;
    int acc = bias[ch];
    for (int kh = 0; kh < 3; ++kh) {
        int hxr = h + kh - 1;
        if ((unsigned)hxr >= 56u) continue;
        for (int kw = 0; kw < 3; ++kw) {
            int wx = w + kw - 1;
            if ((unsigned)wx >= 56u) continue;
            const int* xp = x + ((n * 56 + hxr) * 56 + wx) * 64;
            const int* wp = wgt + ch * KTOT + (kh * 3 + kw) * 64;
            for (int ic = 0; ic < 64; ++ic) acc += xp[ic] * wp[ic];
        }
    }
    out[idx] = acc;
}

// ---------------------------------------------------------------------------
extern "C" void kernel_launch(void* const* d_in, const int* in_sizes, int n_in,
                              void* d_out, int out_size, void* d_ws, size_t ws_size,
                              hipStream_t stream) {
    const int* x    = (const int*)d_in[0];
    const int* wgt  = (const int*)d_in[1];
    const int* bias = (const int*)d_in[2];
    int* out = (int*)d_out;

    if (ws_size >= (size_t)(N_W + 8192)) {
        char* w8 = (char*)d_ws;              // N_W bytes + 8KB prefetch tail
        pack_w_kernel<<<N_W / 4 / 256, 256, 0, stream>>>(wgt, (unsigned int*)w8);
        conv_halo_kernel<<<3136, 256, 0, stream>>>(x, w8, bias, out);
    } else {
        conv_naive_kernel<<<(N_OUT + 255) / 256, 256, 0, stream>>>(x, wgt, bias, out);
    }
}